// Round 6
// baseline (205.780 us; speedup 1.0000x reference)
//
#include <hip/hip_runtime.h>

typedef unsigned short u16;
typedef __attribute__((ext_vector_type(8))) short frag8;   // 8 bf16 (4 VGPRs)
typedef __attribute__((ext_vector_type(4))) float f32x4;   // MFMA accumulator

__device__ __forceinline__ u16 f2bf(float f) {
  unsigned u; __builtin_memcpy(&u, &f, 4);
  u = (u + 0x7FFFu + ((u >> 16) & 1u)) >> 16;   // RNE
  return (u16)u;
}
__device__ __forceinline__ float sel4(int s, float a, float b, float c, float d) {
  return s == 0 ? a : (s == 1 ? b : (s == 2 ? c : d));
}

#define FSTRIDE 24    // feats row stride (bf16 units)
#define HSTRIDE 264   // h row stride (bf16 units), +8 pad
#define ESTRIDE 68    // embT row stride (f32 units)
// LDS:
//   hS    u16 [64][264] @ 0      (33792 B)
//   embS  f32 [64][68]  @ 0      (17408 B)  alias hS lower half
//   grayS f32 [8][512]  @ 17408  (16384 B)  alias hS upper half (disjoint embS)
//   featS u16 [64][24]  @ 33792  (3072 B)
//   b1S   f32 [256]     @ 36864  (1024 B)
#define SMEM_BYTES 37888

__device__ __forceinline__ void load_tile(float4 (&R)[12], const float* __restrict__ x,
                                          int b, int gy, int r, int c0) {
  const float* base = x + ((size_t)(b * 3) * 512 + (size_t)gy * 8 + r) * 512 + c0;
  #pragma unroll
  for (int ch = 0; ch < 3; ++ch)
    #pragma unroll
    for (int q = 0; q < 4; ++q)
      R[ch * 4 + q] = ((const float4*)(base + ch * 262144))[q];
}

__global__ __launch_bounds__(256, 4)
void dct_mlp_fused(const float* __restrict__ x,
                   const float* __restrict__ W1, const float* __restrict__ b1,
                   const float* __restrict__ W2, const float* __restrict__ b2,
                   float* __restrict__ out) {
  __shared__ __align__(16) char smem[SMEM_BYTES];
  u16*   hS    = (u16*)smem;               // [64][264]
  float* embS  = (float*)smem;             // [64][68], aliases hS
  float* grayS = (float*)(smem + 17408);   // [8][512], aliases hS upper half
  u16*   featS = (u16*)(smem + 33792);     // [64][24]
  float* b1S   = (float*)(smem + 36864);   // [256]

  const int t    = threadIdx.x;
  const int lane = t & 63;
  const int w    = t >> 6;          // wave 0..3
  const int quad = lane >> 4;       // 0..3
  const int l16  = lane & 15;
  const int r    = t >> 5;          // gray row 0..7
  const int c0   = (t & 31) * 16;   // gray col chunk

  b1S[t] = b1[t];                   // bias to LDS (saves 16 persistent VGPRs)

  // ---- Weight fragments, loaded once per block ----
  frag8 aW1[4];
  for (int nt = 0; nt < 4; ++nt) {
    int n = (w * 4 + nt) * 16 + l16;
    frag8 f;
    for (int j = 0; j < 8; ++j) {
      int k = quad * 8 + j;
      f[j] = (k < 16) ? (short)f2bf(W1[k * 256 + n]) : (short)0;
    }
    aW1[nt] = f;
  }
  frag8 bW2[8];
  const int n3 = w * 16 + l16;      // output channel
  for (int s = 0; s < 8; ++s) {
    frag8 f;
    for (int j = 0; j < 8; ++j) {
      int c = s * 32 + quad * 8 + j;
      f[j] = (short)f2bf(W2[c * 64 + n3]);
    }
    bW2[s] = f;
  }
  const float b2v = b2[n3];

  float4 Rc[12], Rn[12];
  {
    const int tile0 = blockIdx.x;
    load_tile(Rc, x, tile0 >> 6, tile0 & 63, r, c0);
  }

  #pragma unroll
  for (int it = 0; it < 2; ++it) {
    const int tile = blockIdx.x + 1024 * it;
    const int gy = tile & 63;
    const int b  = tile >> 6;

    // ---- Gray from registers -> LDS (disjoint from embS; hS reads done) ----
    {
      float* gdst = grayS + r * 512 + c0;
      #pragma unroll
      for (int q = 0; q < 4; ++q) {
        float4 a = Rc[q], g = Rc[4 + q], c = Rc[8 + q];
        float4 o;
        o.x = 0.299f * a.x + 0.587f * g.x + 0.114f * c.x;
        o.y = 0.299f * a.y + 0.587f * g.y + 0.114f * c.y;
        o.z = 0.299f * a.z + 0.587f * g.z + 0.114f * c.z;
        o.w = 0.299f * a.w + 0.587f * g.w + 0.114f * c.w;
        ((float4*)gdst)[q] = o;
      }
    }
    __syncthreads();

    // ---- Prefetch next tile's x: in flight across DCT+GEMM1+GEMM2 ----
    if (it == 0) {
      const int t2 = blockIdx.x + 1024;
      load_tile(Rn, x, t2 >> 6, t2 & 63, r, c0);
    }

    // ---- DCT from LDS gray (broadcast across the 4 kr-dup lanes) ----
    {
      const int p  = t >> 2;
      const int kr = t & 3;
      float dk[8];
      dk[0] = sel4(kr, 0.35355339f,  0.49039264f,  0.46193977f,  0.41573481f);
      dk[1] = sel4(kr, 0.35355339f,  0.41573481f,  0.19134172f, -0.09754516f);
      dk[2] = sel4(kr, 0.35355339f,  0.27778512f, -0.19134172f, -0.49039264f);
      dk[3] = sel4(kr, 0.35355339f,  0.09754516f, -0.46193977f, -0.27778512f);
      dk[4] = sel4(kr, 0.35355339f, -0.09754516f, -0.46193977f,  0.27778512f);
      dk[5] = sel4(kr, 0.35355339f, -0.27778512f, -0.19134172f,  0.49039264f);
      dk[6] = sel4(kr, 0.35355339f, -0.41573481f,  0.19134172f,  0.09754516f);
      dk[7] = sel4(kr, 0.35355339f, -0.49039264f,  0.46193977f, -0.41573481f);

      float tmp[8] = {0.f,0.f,0.f,0.f,0.f,0.f,0.f,0.f};
      #pragma unroll
      for (int i = 0; i < 8; ++i) {
        const float* row = grayS + i * 512 + p * 8;
        float4 lo = ((const float4*)row)[0];
        float4 hi = ((const float4*)row)[1];
        float d = dk[i];
        tmp[0] = fmaf(d, lo.x, tmp[0]); tmp[1] = fmaf(d, lo.y, tmp[1]);
        tmp[2] = fmaf(d, lo.z, tmp[2]); tmp[3] = fmaf(d, lo.w, tmp[3]);
        tmp[4] = fmaf(d, hi.x, tmp[4]); tmp[5] = fmaf(d, hi.y, tmp[5]);
        tmp[6] = fmaf(d, hi.z, tmp[6]); tmp[7] = fmaf(d, hi.w, tmp[7]);
      }
      const float D4c[4][8] = {
        { 0.35355339f, 0.35355339f, 0.35355339f, 0.35355339f,
          0.35355339f, 0.35355339f, 0.35355339f, 0.35355339f},
        { 0.49039264f, 0.41573481f, 0.27778512f, 0.09754516f,
         -0.09754516f,-0.27778512f,-0.41573481f,-0.49039264f},
        { 0.46193977f, 0.19134172f,-0.19134172f,-0.46193977f,
         -0.46193977f,-0.19134172f, 0.19134172f, 0.46193977f},
        { 0.41573481f,-0.09754516f,-0.49039264f,-0.27778512f,
          0.27778512f, 0.49039264f, 0.09754516f,-0.41573481f}
      };
      float cc[4] = {0.f, 0.f, 0.f, 0.f};
      #pragma unroll
      for (int l = 0; l < 4; ++l)
        #pragma unroll
        for (int j = 0; j < 8; ++j)
          cc[l] = fmaf(tmp[j], D4c[l][j], cc[l]);
      ushort4 fv;
      fv.x = f2bf(cc[0]); fv.y = f2bf(cc[1]); fv.z = f2bf(cc[2]); fv.w = f2bf(cc[3]);
      *(ushort4*)(featS + p * FSTRIDE + (t & 3) * 4) = fv;
    }
    __syncthreads();   // featS ready; grayS reads done (GEMM1 overwrites it)

    // ---- GEMM1 (swapped): h^T = W1^T @ feats^T, relu -> hS bf16 ----
    for (int pt = 0; pt < 4; ++pt) {
      frag8 bf = {0,0,0,0,0,0,0,0};
      if (quad < 2)
        bf = *(const frag8*)(featS + (pt * 16 + l16) * FSTRIDE + quad * 8);
      for (int nt = 0; nt < 4; ++nt) {
        float4 bb = *(const float4*)(b1S + (w * 4 + nt) * 16 + quad * 4);
        f32x4 acc = {bb.x, bb.y, bb.z, bb.w};
        acc = __builtin_amdgcn_mfma_f32_16x16x32_bf16(aW1[nt], bf, acc, 0, 0, 0);
        ushort4 hv;
        hv.x = f2bf(acc[0] > 0.f ? acc[0] : 0.f);
        hv.y = f2bf(acc[1] > 0.f ? acc[1] : 0.f);
        hv.z = f2bf(acc[2] > 0.f ? acc[2] : 0.f);
        hv.w = f2bf(acc[3] > 0.f ? acc[3] : 0.f);
        *(ushort4*)(hS + (pt * 16 + l16) * HSTRIDE + (w * 4 + nt) * 16 + quad * 4) = hv;
      }
    }
    __syncthreads();

    // ---- GEMM2 (h[64x256] @ W2[256x64] + b2) ----
    f32x4 accs[4];
    for (int mt = 0; mt < 4; ++mt) {
      f32x4 acc = {b2v, b2v, b2v, b2v};
      const u16* hrow = hS + (mt * 16 + l16) * HSTRIDE;
      #pragma unroll
      for (int s = 0; s < 8; ++s) {
        frag8 a = *(const frag8*)(hrow + s * 32 + quad * 8);  // ds_read_b128
        acc = __builtin_amdgcn_mfma_f32_16x16x32_bf16(a, bW2[s], acc, 0, 0, 0);
      }
      accs[mt] = acc;
    }
    __syncthreads();   // hS reads done; embS may overwrite

    for (int mt = 0; mt < 4; ++mt) {
      float4 v; v.x = accs[mt][0]; v.y = accs[mt][1]; v.z = accs[mt][2]; v.w = accs[mt][3];
      *(float4*)(embS + n3 * ESTRIDE + mt * 16 + quad * 4) = v;
    }
    __syncthreads();

    // ---- Coalesced epilogue (reads embS; next gray write is disjoint) ----
    {
      const int ch = t >> 2;
      const int cc = t & 3;
      const float* src = embS + ch * ESTRIDE + cc * 16;
      float* dst = out + ((((size_t)b * 64 + ch) * 64) + gy) * 64 + cc * 16;
      #pragma unroll
      for (int q = 0; q < 4; ++q)
        ((float4*)dst)[q] = ((const float4*)src)[q];
    }

    #pragma unroll
    for (int q = 0; q < 12; ++q) Rc[q] = Rn[q];
  }
}

extern "C" void kernel_launch(void* const* d_in, const int* in_sizes, int n_in,
                              void* d_out, int out_size, void* d_ws, size_t ws_size,
                              hipStream_t stream) {
  const float* x  = (const float*)d_in[0];
  const float* W1 = (const float*)d_in[1];
  const float* b1 = (const float*)d_in[2];
  const float* W2 = (const float*)d_in[3];
  const float* b2 = (const float*)d_in[4];
  float* out = (float*)d_out;
  dct_mlp_fused<<<dim3(1024, 1, 1), dim3(256, 1, 1), 0, stream>>>(x, W1, b1, W2, b2, out);
}

// Round 7
// 174.340 us; speedup vs baseline: 1.1803x; 1.1803x over previous
//
#include <hip/hip_runtime.h>

typedef unsigned short u16;
typedef __attribute__((ext_vector_type(8))) short frag8;   // 8 bf16 (4 VGPRs)
typedef __attribute__((ext_vector_type(4))) float f32x4;   // MFMA accumulator

__device__ __forceinline__ u16 f2bf(float f) {
  unsigned u; __builtin_memcpy(&u, &f, 4);
  u = (u + 0x7FFFu + ((u >> 16) & 1u)) >> 16;   // RNE
  return (u16)u;
}
__device__ __forceinline__ float sel4(int s, float a, float b, float c, float d) {
  return s == 0 ? a : (s == 1 ? b : (s == 2 ? c : d));
}

#define FSTRIDE 24    // feats row stride (bf16 units)
#define HSTRIDE 264   // h row stride (bf16 units), +8 pad
#define ESTRIDE 68    // embT row stride (f32 units)
// LDS:
//   hS    u16 [64][264] @ 0      (33792 B)
//   embS  f32 [64][68]  @ 0      (17408 B)  alias hS lower half
//   grayS f32 [8][512]  @ 17408  (16384 B)  alias hS upper half (disjoint embS)
//   featS u16 [64][24]  @ 33792  (3072 B)
//   b1S   f32 [256]     @ 36864  (1024 B)
#define SMEM_BYTES 37888

#define NTILES 4      // tiles per block; grid = 2048/NTILES = 512 (2 blocks/CU)

__device__ __forceinline__ void load_tile(float4 (&R)[12], const float* __restrict__ x,
                                          int tile, int r, int c0) {
  const int gy = tile & 63;
  const int b  = tile >> 6;
  const float* base = x + ((size_t)(b * 3) * 512 + (size_t)gy * 8 + r) * 512 + c0;
  #pragma unroll
  for (int ch = 0; ch < 3; ++ch)
    #pragma unroll
    for (int q = 0; q < 4; ++q)
      R[ch * 4 + q] = ((const float4*)(base + ch * 262144))[q];
}

// min-waves/EU = 2 -> ~256 VGPR budget: Rc+Rn (96) + weight frags (48) must
// stay in registers. Round-6's (256,4) caused a 50 MB scratch spill.
__global__ __launch_bounds__(256, 2)
void dct_mlp_fused(const float* __restrict__ x,
                   const float* __restrict__ W1, const float* __restrict__ b1,
                   const float* __restrict__ W2, const float* __restrict__ b2,
                   float* __restrict__ out) {
  __shared__ __align__(16) char smem[SMEM_BYTES];
  u16*   hS    = (u16*)smem;               // [64][264]
  float* embS  = (float*)smem;             // [64][68], aliases hS
  float* grayS = (float*)(smem + 17408);   // [8][512], aliases hS upper half
  u16*   featS = (u16*)(smem + 33792);     // [64][24]
  float* b1S   = (float*)(smem + 36864);   // [256]

  const int t    = threadIdx.x;
  const int lane = t & 63;
  const int w    = t >> 6;          // wave 0..3
  const int quad = lane >> 4;       // 0..3
  const int l16  = lane & 15;
  const int r    = t >> 5;          // gray row 0..7
  const int c0   = (t & 31) * 16;   // gray col chunk

  // First pixel load issues before the (L2-hot) weight loads.
  float4 Rc[12], Rn[12];
  load_tile(Rc, x, blockIdx.x, r, c0);

  b1S[t] = b1[t];                   // bias to LDS

  // ---- Weight fragments, loaded once per block (amortized over 4 tiles) ----
  frag8 aW1[4];
  for (int nt = 0; nt < 4; ++nt) {
    int n = (w * 4 + nt) * 16 + l16;
    frag8 f;
    for (int j = 0; j < 8; ++j) {
      int k = quad * 8 + j;
      f[j] = (k < 16) ? (short)f2bf(W1[k * 256 + n]) : (short)0;
    }
    aW1[nt] = f;
  }
  frag8 bW2[8];
  const int n3 = w * 16 + l16;      // output channel
  for (int s = 0; s < 8; ++s) {
    frag8 f;
    for (int j = 0; j < 8; ++j) {
      int c = s * 32 + quad * 8 + j;
      f[j] = (short)f2bf(W2[c * 64 + n3]);
    }
    bW2[s] = f;
  }
  const float b2v = b2[n3];

  #pragma unroll
  for (int it = 0; it < NTILES; ++it) {
    const int tile = blockIdx.x + 512 * it;
    const int gy = tile & 63;
    const int b  = tile >> 6;

    // ---- Gray from registers -> LDS ----
    {
      float* gdst = grayS + r * 512 + c0;
      #pragma unroll
      for (int q = 0; q < 4; ++q) {
        float4 a = Rc[q], g = Rc[4 + q], c = Rc[8 + q];
        float4 o;
        o.x = 0.299f * a.x + 0.587f * g.x + 0.114f * c.x;
        o.y = 0.299f * a.y + 0.587f * g.y + 0.114f * c.y;
        o.z = 0.299f * a.z + 0.587f * g.z + 0.114f * c.z;
        o.w = 0.299f * a.w + 0.587f * g.w + 0.114f * c.w;
        ((float4*)gdst)[q] = o;
      }
    }
    __syncthreads();

    // ---- Prefetch next tile: 12 loads in flight across DCT+GEMM1+GEMM2 ----
    if (it < NTILES - 1)
      load_tile(Rn, x, blockIdx.x + 512 * (it + 1), r, c0);

    // ---- DCT from LDS gray ----
    {
      const int p  = t >> 2;
      const int kr = t & 3;
      float dk[8];
      dk[0] = sel4(kr, 0.35355339f,  0.49039264f,  0.46193977f,  0.41573481f);
      dk[1] = sel4(kr, 0.35355339f,  0.41573481f,  0.19134172f, -0.09754516f);
      dk[2] = sel4(kr, 0.35355339f,  0.27778512f, -0.19134172f, -0.49039264f);
      dk[3] = sel4(kr, 0.35355339f,  0.09754516f, -0.46193977f, -0.27778512f);
      dk[4] = sel4(kr, 0.35355339f, -0.09754516f, -0.46193977f,  0.27778512f);
      dk[5] = sel4(kr, 0.35355339f, -0.27778512f, -0.19134172f,  0.49039264f);
      dk[6] = sel4(kr, 0.35355339f, -0.41573481f,  0.19134172f,  0.09754516f);
      dk[7] = sel4(kr, 0.35355339f, -0.49039264f,  0.46193977f, -0.41573481f);

      float tmp[8] = {0.f,0.f,0.f,0.f,0.f,0.f,0.f,0.f};
      #pragma unroll
      for (int i = 0; i < 8; ++i) {
        const float* row = grayS + i * 512 + p * 8;
        float4 lo = ((const float4*)row)[0];
        float4 hi = ((const float4*)row)[1];
        float d = dk[i];
        tmp[0] = fmaf(d, lo.x, tmp[0]); tmp[1] = fmaf(d, lo.y, tmp[1]);
        tmp[2] = fmaf(d, lo.z, tmp[2]); tmp[3] = fmaf(d, lo.w, tmp[3]);
        tmp[4] = fmaf(d, hi.x, tmp[4]); tmp[5] = fmaf(d, hi.y, tmp[5]);
        tmp[6] = fmaf(d, hi.z, tmp[6]); tmp[7] = fmaf(d, hi.w, tmp[7]);
      }
      const float D4c[4][8] = {
        { 0.35355339f, 0.35355339f, 0.35355339f, 0.35355339f,
          0.35355339f, 0.35355339f, 0.35355339f, 0.35355339f},
        { 0.49039264f, 0.41573481f, 0.27778512f, 0.09754516f,
         -0.09754516f,-0.27778512f,-0.41573481f,-0.49039264f},
        { 0.46193977f, 0.19134172f,-0.19134172f,-0.46193977f,
         -0.46193977f,-0.19134172f, 0.19134172f, 0.46193977f},
        { 0.41573481f,-0.09754516f,-0.49039264f,-0.27778512f,
          0.27778512f, 0.49039264f, 0.09754516f,-0.41573481f}
      };
      float cc[4] = {0.f, 0.f, 0.f, 0.f};
      #pragma unroll
      for (int l = 0; l < 4; ++l)
        #pragma unroll
        for (int j = 0; j < 8; ++j)
          cc[l] = fmaf(tmp[j], D4c[l][j], cc[l]);
      ushort4 fv;
      fv.x = f2bf(cc[0]); fv.y = f2bf(cc[1]); fv.z = f2bf(cc[2]); fv.w = f2bf(cc[3]);
      *(ushort4*)(featS + p * FSTRIDE + kr * 4) = fv;
    }
    __syncthreads();   // featS ready; grayS reads done (GEMM1 overwrites it)

    // ---- GEMM1 (swapped): h^T = W1^T @ feats^T, relu -> hS bf16 ----
    for (int pt = 0; pt < 4; ++pt) {
      frag8 bf = {0,0,0,0,0,0,0,0};
      if (quad < 2)
        bf = *(const frag8*)(featS + (pt * 16 + l16) * FSTRIDE + quad * 8);
      for (int nt = 0; nt < 4; ++nt) {
        float4 bb = *(const float4*)(b1S + (w * 4 + nt) * 16 + quad * 4);
        f32x4 acc = {bb.x, bb.y, bb.z, bb.w};
        acc = __builtin_amdgcn_mfma_f32_16x16x32_bf16(aW1[nt], bf, acc, 0, 0, 0);
        ushort4 hv;
        hv.x = f2bf(acc[0] > 0.f ? acc[0] : 0.f);
        hv.y = f2bf(acc[1] > 0.f ? acc[1] : 0.f);
        hv.z = f2bf(acc[2] > 0.f ? acc[2] : 0.f);
        hv.w = f2bf(acc[3] > 0.f ? acc[3] : 0.f);
        *(ushort4*)(hS + (pt * 16 + l16) * HSTRIDE + (w * 4 + nt) * 16 + quad * 4) = hv;
      }
    }
    __syncthreads();

    // ---- GEMM2 (h[64x256] @ W2[256x64] + b2) ----
    f32x4 accs[4];
    for (int mt = 0; mt < 4; ++mt) {
      f32x4 acc = {b2v, b2v, b2v, b2v};
      const u16* hrow = hS + (mt * 16 + l16) * HSTRIDE;
      #pragma unroll
      for (int s = 0; s < 8; ++s) {
        frag8 a = *(const frag8*)(hrow + s * 32 + quad * 8);  // ds_read_b128
        acc = __builtin_amdgcn_mfma_f32_16x16x32_bf16(a, bW2[s], acc, 0, 0, 0);
      }
      accs[mt] = acc;
    }
    __syncthreads();   // hS reads done; embS may overwrite

    for (int mt = 0; mt < 4; ++mt) {
      float4 v; v.x = accs[mt][0]; v.y = accs[mt][1]; v.z = accs[mt][2]; v.w = accs[mt][3];
      *(float4*)(embS + n3 * ESTRIDE + mt * 16 + quad * 4) = v;
    }
    __syncthreads();

    // ---- Coalesced epilogue (reads embS; next gray write is disjoint) ----
    {
      const int ch = t >> 2;
      const int cc = t & 3;
      const float* src = embS + ch * ESTRIDE + cc * 16;
      float* dst = out + ((((size_t)b * 64 + ch) * 64) + gy) * 64 + cc * 16;
      #pragma unroll
      for (int q = 0; q < 4; ++q)
        ((float4*)dst)[q] = ((const float4*)src)[q];
    }

    if (it < NTILES - 1) {
      #pragma unroll
      for (int q = 0; q < 12; ++q) Rc[q] = Rn[q];
    }
  }
}

extern "C" void kernel_launch(void* const* d_in, const int* in_sizes, int n_in,
                              void* d_out, int out_size, void* d_ws, size_t ws_size,
                              hipStream_t stream) {
  const float* x  = (const float*)d_in[0];
  const float* W1 = (const float*)d_in[1];
  const float* b1 = (const float*)d_in[2];
  const float* W2 = (const float*)d_in[3];
  const float* b2 = (const float*)d_in[4];
  float* out = (float*)d_out;
  dct_mlp_fused<<<dim3(512, 1, 1), dim3(256, 1, 1), 0, stream>>>(x, W1, b1, W2, b2, out);
}